// Round 17
// baseline (359.444 us; speedup 1.0000x reference)
//
#include <hip/hip_runtime.h>
#include <cstdint>
#include <cstddef>

#define T_ 3
#define B_ 2
#define Y_ 192
#define X_ 192
#define YX_ 36864          // Y_*X_
#define N_ 221184          // T_*B_*Y_*X_
#define NS_ 73728          // B_*Y_*X_

typedef __attribute__((ext_vector_type(8))) _Float16 h16x8;
typedef __attribute__((ext_vector_type(4))) float f32x4;
typedef __attribute__((ext_vector_type(2))) float f32x2;
typedef __attribute__((ext_vector_type(2))) _Float16 h16x2;
typedef unsigned short u16;
typedef unsigned int u32;

__device__ __forceinline__ u16 f2h(float f){
  return __builtin_bit_cast(u16, (_Float16)f);   // v_cvt_f16_f32, RNE
}
__device__ __forceinline__ int clampi(int v, int lo, int hi){ return v < lo ? lo : (v > hi ? hi : v); }
__device__ __forceinline__ h16x2 shflh(h16x2 v, int m){
  u32 u = __builtin_bit_cast(u32, v);
  u = __shfl_xor(u, m);
  return __builtin_bit_cast(h16x2, u);
}

// fp16 packed dot: v_dot2_f32_f16 (VOP3P)
#if __has_builtin(__builtin_amdgcn_fdot2)
__device__ __forceinline__ float dot2h(u32 a, u32 b, float c){
  return __builtin_amdgcn_fdot2(__builtin_bit_cast(h16x2, a),
                                __builtin_bit_cast(h16x2, b), c, false);
}
#else
__device__ __forceinline__ float dot2h(u32 a, u32 b, float c){
  const h16x2 ha = __builtin_bit_cast(h16x2, a);
  const h16x2 hb = __builtin_bit_cast(h16x2, b);
  return fmaf((float)ha.y, (float)hb.y, fmaf((float)ha.x, (float)hb.x, c));
}
#endif

#if __has_builtin(__builtin_amdgcn_exp2f)
__device__ __forceinline__ float fexp2(float x){ return __builtin_amdgcn_exp2f(x); }
#else
__device__ __forceinline__ float fexp2(float x){ return exp2f(x); }
#endif

// Q prescale: 1/sqrt(F) * log2(e), so score exp() becomes exp2() with no extra mul
#define QSCALE 0.36067376022224085f

// ---------------- kernel 0: weights -> fp16 n-major; spatial_emb -> fp16 ----------------
__global__ __launch_bounds__(256) void wt_kernel(
    const float* __restrict__ Wq, const float* __restrict__ Wk,
    const float* __restrict__ Wv, const float* __restrict__ Wo,
    const float* __restrict__ spatial_emb, u16* __restrict__ WT, u16* __restrict__ se_h){
  int idx = blockIdx.x * 256 + threadIdx.x;
  if (idx < 65536){
    int g = idx >> 14;
    int r = (idx >> 7) & 127;                   // k
    int c = idx & 127;                          // n
    const float* W = (g == 0) ? Wq : (g == 1) ? Wk : (g == 2) ? Wv : Wo;
    WT[g * 16384 + c * 128 + r] = f2h(W[r * 128 + c]);
  } else if (idx < 65536 + 3200){
    se_h[idx - 65536] = f2h(spatial_emb[idx - 65536]);
  }
}

// ---------------- kernel 1: fused QKV projection, persistent A-frags, fp16 MFMA ----------
// One block = 128 rows. A-tile loaded ONCE into fp16 register fragments (1 cvt/elem),
// g-loop {Q,K,V}: 64 MFMA + halved-LDS epilogue (2 column passes). Q,K,V all fp16.
// 32KB tile + launch_bounds(256,4): 4 blocks/CU (VGPR cap 128 >= ~115 live).
__global__ __launch_bounds__(256, 4) void qkv_kernel(
    const float* __restrict__ frames, const u16* __restrict__ WT,
    u16* __restrict__ Qb, u16* __restrict__ Kb, u16* __restrict__ Vb,
    const float* __restrict__ temp_emb, const float* __restrict__ spatial_emb){
  __shared__ float tile[128 * 64];
  const int tid = threadIdx.x;
  const int w = tid >> 6, l = tid & 63;
  const int l16 = l & 15, lg = l >> 4;
  const int m0 = blockIdx.x * 128;

  // ---- load A fragments once (fp16), reused by all 3 GEMMs ----
  h16x8 af[4][2];
  #pragma unroll
  for (int ks = 0; ks < 4; ++ks)
    #pragma unroll
    for (int mr = 0; mr < 2; ++mr){
      const float* ap = frames + (size_t)(m0 + w * 32 + mr * 16 + l16) * 128 + ks * 32 + lg * 8;
      const f32x4 a0 = *(const f32x4*)ap;
      const f32x4 a1 = *(const f32x4*)(ap + 4);
      h16x8 t;
      t[0] = (_Float16)a0[0]; t[1] = (_Float16)a0[1];
      t[2] = (_Float16)a0[2]; t[3] = (_Float16)a0[3];
      t[4] = (_Float16)a1[0]; t[5] = (_Float16)a1[1];
      t[6] = (_Float16)a1[2]; t[7] = (_Float16)a1[3];
      af[ks][mr] = t;
    }

  #pragma unroll
  for (int g = 0; g < 3; ++g){
    const u16* wt = WT + g * 16384;
    f32x4 acc[2][8];
    #pragma unroll
    for (int mr = 0; mr < 2; ++mr)
      #pragma unroll
      for (int nf = 0; nf < 8; ++nf)
        acc[mr][nf] = (f32x4){0.f, 0.f, 0.f, 0.f};

    #pragma unroll
    for (int ks = 0; ks < 4; ++ks)
      #pragma unroll
      for (int nf = 0; nf < 8; ++nf){
        const h16x8 bf = *(const h16x8*)(wt + (nf * 16 + l16) * 128 + ks * 32 + lg * 8);
        acc[0][nf] = __builtin_amdgcn_mfma_f32_16x16x32_f16(af[ks][0], bf, acc[0][nf], 0, 0, 0);
        acc[1][nf] = __builtin_amdgcn_mfma_f32_16x16x32_f16(af[ks][1], bf, acc[1][nf], 0, 0, 0);
      }

    u16* outp = (g == 0) ? Qb : (g == 1) ? Kb : Vb;
    #pragma unroll
    for (int h2 = 0; h2 < 2; ++h2){
      if (g > 0 || h2 > 0) __syncthreads();   // previous epilogue reads done
      #pragma unroll
      for (int mr = 0; mr < 2; ++mr)
        #pragma unroll
        for (int nf4 = 0; nf4 < 4; ++nf4){
          const int nf = h2 * 4 + nf4;
          #pragma unroll
          for (int i = 0; i < 4; ++i)
            tile[(w * 32 + mr * 16 + lg * 4 + i) * 64 + nf4 * 16 + l16] = acc[mr][nf][i];
        }
      __syncthreads();

      #pragma unroll
      for (int it = 0; it < 8; ++it){
        const int idx = it * 256 + tid;
        const int r = idx >> 4;               // 0..127
        const int c4 = (idx & 15) * 4;        // 0..60
        f32x4 v = *(const f32x4*)&tile[r * 64 + c4];
        const int p = m0 + r;
        const int col = h2 * 64 + c4;
        const int t = p / (B_ * YX_);
        if (g <= 1){                          // temporal emb for Q and K
          const float* te = temp_emb + t * 128 + col;
          v[0] += te[0]; v[1] += te[1]; v[2] += te[2]; v[3] += te[3];
        }
        if (g == 0){                          // query spatial emb + QSCALE prescale
          const int yx = p % YX_;
          const int y = yx / X_, x = yx % X_;
          const int yrel = y - clampi(y, 2, Y_ - 3) + 2;
          const int xrel = x - clampi(x, 2, X_ - 3) + 2;
          const float* se = spatial_emb + (yrel * 5 + xrel) * 128 + col;
          v[0] = (v[0] + se[0]) * QSCALE; v[1] = (v[1] + se[1]) * QSCALE;
          v[2] = (v[2] + se[2]) * QSCALE; v[3] = (v[3] + se[3]) * QSCALE;
        }
        uint2 pk;                             // Q,K,V all packed fp16
        pk.x = (u32)f2h(v[0]) | ((u32)f2h(v[1]) << 16);
        pk.y = (u32)f2h(v[2]) | ((u32)f2h(v[3]) << 16);
        *(uint2*)(outp + (size_t)p * 128 + col) = pk;
      }
    }
  }
}

// ---------------- kernel 2: scalar attention, 2 sites x 4 key-slots x 8 heads per wave ----------
// lane (s2=l>>5, slot=(l>>3)&3, h=l&7): site s2, head h (16ch), keys slot, slot+4, ...
// V fp16, PV accumulated as fp16 pairs via v_pk_fma_f16 (zero unpack); merge shuffles
// one u32 per pair. LDS 39KB -> 4 blocks/CU, 128-VGPR budget, no spill. Output fp16.
__global__ __launch_bounds__(256) void attn_kernel(
    const u16* __restrict__ Kb, const u16* __restrict__ Vb,
    u16* __restrict__ Qb, const u16* __restrict__ se_h){
  __shared__ float qse[4][2][1200];         // [wave][site2][q*200 + s*8 + h] (pad -> 4 blocks/CU)
  __shared__ u32 tbl[80];                   // byte offset (x256) | s*8 in low byte
  const int tid = threadIdx.x;
  const int w = tid >> 6, l = tid & 63;
  const int s2 = l >> 5, slot = (l >> 3) & 3, h = l & 7;

  if (tid < 80){                            // offset table (padded: 75..79 -> key 74)
    const int kk = tid > 74 ? 74 : tid;
    const int t = kk / 25, s = kk - t * 25;
    const int dy = s / 5, dx = s - dy * 5;
    tbl[tid] = (u32)((((t * (B_ * Y_) + dy) * X_ + dx) * 256) | (s * 8));
  }

  // XCD-aware swizzle: 9216 blocks = 8 XCDs x 1152 contiguous (48-row slab each)
  const int bid = blockIdx.x;
  const int sw = (bid & 7) * 1152 + (bid >> 3);
  const int site = sw * 8 + w * 2 + s2;
  const int b = site / YX_;
  const int yx = site % YX_;
  const int y = yx / X_, x = yx % X_;
  const int yc = clampi(y, 2, 189), xc = clampi(x, 2, 189);
  const u32 sbase = (u32)(((b * Y_ + (yc - 2)) * X_ + (xc - 2)) * 256 + h * 32);
  const char* Kc = (const char*)Kb;
  const char* Vc = (const char*)Vb;

  // Q packed fp16 (prescaled by QSCALE, + temp & query-spatial emb)
  u32 qp[3][8];
  #pragma unroll
  for (int q = 0; q < 3; ++q){
    const u16* qptr = Qb + ((size_t)((q * B_ + b) * Y_ + y) * X_ + x) * 128 + h * 16;
    const uint4 a = *(const uint4*)qptr;
    const uint4 c = *(const uint4*)(qptr + 8);
    qp[q][0] = a.x; qp[q][1] = a.y; qp[q][2] = a.z; qp[q][3] = a.w;
    qp[q][4] = c.x; qp[q][5] = c.y; qp[q][6] = c.z; qp[q][7] = c.w;
  }

  // qse[q][so][h] = Qs . spatial_emb[so] (per head), so striped over the 4 slots
  float* qsl = &qse[w][s2][0];
  #pragma unroll
  for (int sj = 0; sj < 7; ++sj){
    const int so = sj * 4 + slot;
    if (so < 25){
      const u16* sp = se_h + so * 128 + h * 16;
      const uint4 e0 = *(const uint4*)sp;
      const uint4 e1 = *(const uint4*)(sp + 8);
      u32 ep[8] = {e0.x, e0.y, e0.z, e0.w, e1.x, e1.y, e1.z, e1.w};
      #pragma unroll
      for (int q = 0; q < 3; ++q){
        float d = 0.f;
        #pragma unroll
        for (int i = 0; i < 8; ++i) d = dot2h(qp[q][i], ep[i], d);
        qsl[q * 200 + so * 8 + h] = d;
      }
    }
  }
  __syncthreads();

  // preload ALL 19 table entries into registers: no LDS reads on the address path
  u32 ev[19];
  #pragma unroll
  for (int j = 0; j < 19; ++j) ev[j] = tbl[j * 4 + slot];

  float ll[3] = {0.f, 0.f, 0.f};
  h16x2 acc[3][8];
  #pragma unroll
  for (int q = 0; q < 3; ++q)
    #pragma unroll
    for (int i = 0; i < 8; ++i) acc[q][i] = (h16x2){(_Float16)0.f, (_Float16)0.f};

  #pragma unroll
  for (int j = 0; j < 19; ++j){
    const u32 e = ev[j];
    const u32 boff = sbase + (e & 0xffffff00u);
    const int s8 = (int)(e & 0xffu);
    const uint4 k0 = *(const uint4*)(Kc + boff);
    const uint4 k1 = *(const uint4*)(Kc + boff + 16);
    const uint4 v0 = *(const uint4*)(Vc + boff);
    const uint4 v1 = *(const uint4*)(Vc + boff + 16);
    h16x2 hv[8];
    hv[0] = __builtin_bit_cast(h16x2, v0.x); hv[1] = __builtin_bit_cast(h16x2, v0.y);
    hv[2] = __builtin_bit_cast(h16x2, v0.z); hv[3] = __builtin_bit_cast(h16x2, v0.w);
    hv[4] = __builtin_bit_cast(h16x2, v1.x); hv[5] = __builtin_bit_cast(h16x2, v1.y);
    hv[6] = __builtin_bit_cast(h16x2, v1.z); hv[7] = __builtin_bit_cast(h16x2, v1.w);

    #pragma unroll
    for (int q = 0; q < 3; ++q){
      // two independent 4-deep dot2 chains (halved critical path)
      float d1 = qsl[q * 200 + s8 + h];
      d1 = dot2h(qp[q][0], k0.x, d1);
      d1 = dot2h(qp[q][1], k0.y, d1);
      d1 = dot2h(qp[q][2], k0.z, d1);
      d1 = dot2h(qp[q][3], k0.w, d1);
      float d2 = dot2h(qp[q][4], k1.x, 0.f);
      d2 = dot2h(qp[q][5], k1.y, d2);
      d2 = dot2h(qp[q][6], k1.z, d2);
      d2 = dot2h(qp[q][7], k1.w, d2);
      float p = fexp2(d1 + d2);
      if (j == 18 && slot == 3) p = 0.f;    // key 75 is padding
      ll[q] += p;
      const _Float16 ph = (_Float16)p;
      h16x2 pp; pp.x = ph; pp.y = ph;
      #pragma unroll
      for (int i = 0; i < 8; ++i) acc[q][i] += pp * hv[i];   // v_pk_fma_f16
    }
  }

  // merge across the 4 key-slot groups (lanes xor 8/16 share the same site & head)
  #pragma unroll
  for (int q = 0; q < 3; ++q){
    ll[q] += __shfl_xor(ll[q], 8);
    ll[q] += __shfl_xor(ll[q], 16);
    #pragma unroll
    for (int i = 0; i < 8; ++i){
      acc[q][i] += shflh(acc[q][i], 8);     // one u32 shuffle + one v_pk_add_f16
      acc[q][i] += shflh(acc[q][i], 16);
    }
  }

  // slot q (<3) stores query-frame q's output (fp16) over its site's Q row
  #pragma unroll
  for (int q = 0; q < 3; ++q){
    if (slot == q){
      const float inv = 1.0f / ll[q];
      uint4 o0, o1;
      {
        const float a0 = (float)acc[q][0].x * inv, a1 = (float)acc[q][0].y * inv;
        const float a2 = (float)acc[q][1].x * inv, a3 = (float)acc[q][1].y * inv;
        const float a4 = (float)acc[q][2].x * inv, a5 = (float)acc[q][2].y * inv;
        const float a6 = (float)acc[q][3].x * inv, a7 = (float)acc[q][3].y * inv;
        o0.x = (u32)f2h(a0) | ((u32)f2h(a1) << 16);
        o0.y = (u32)f2h(a2) | ((u32)f2h(a3) << 16);
        o0.z = (u32)f2h(a4) | ((u32)f2h(a5) << 16);
        o0.w = (u32)f2h(a6) | ((u32)f2h(a7) << 16);
      }
      {
        const float a0 = (float)acc[q][4].x * inv, a1 = (float)acc[q][4].y * inv;
        const float a2 = (float)acc[q][5].x * inv, a3 = (float)acc[q][5].y * inv;
        const float a4 = (float)acc[q][6].x * inv, a5 = (float)acc[q][6].y * inv;
        const float a6 = (float)acc[q][7].x * inv, a7 = (float)acc[q][7].y * inv;
        o1.x = (u32)f2h(a0) | ((u32)f2h(a1) << 16);
        o1.y = (u32)f2h(a2) | ((u32)f2h(a3) << 16);
        o1.z = (u32)f2h(a4) | ((u32)f2h(a5) << 16);
        o1.w = (u32)f2h(a6) | ((u32)f2h(a7) << 16);
      }
      u16* dst = Qb + ((size_t)((q * B_ + b) * Y_ + y) * X_ + x) * 128 + h * 16;
      *(uint4*)dst = o0;
      *(uint4*)(dst + 8) = o1;
    }
  }
}

// ---------------- kernel 3: output projection (attnout x Wout), fp16 MFMA ----------------
__global__ __launch_bounds__(256) void out_kernel(
    const u16* __restrict__ Ab, const u16* __restrict__ WT3, float* __restrict__ out){
  const int tid = threadIdx.x;
  const int w = tid >> 6, l = tid & 63;
  const int l16 = l & 15, lg = l >> 4;
  const int m0 = blockIdx.x * 128;

  f32x4 acc[2][8];
  #pragma unroll
  for (int mr = 0; mr < 2; ++mr)
    #pragma unroll
    for (int nf = 0; nf < 8; ++nf)
      acc[mr][nf] = (f32x4){0.f, 0.f, 0.f, 0.f};

  #pragma unroll
  for (int ks = 0; ks < 4; ++ks){
    h16x8 af[2];
    #pragma unroll
    for (int mr = 0; mr < 2; ++mr)
      af[mr] = *(const h16x8*)(Ab + (size_t)(m0 + w * 32 + mr * 16 + l16) * 128 + ks * 32 + lg * 8);
    #pragma unroll
    for (int nf = 0; nf < 8; ++nf){
      const h16x8 bf = *(const h16x8*)(WT3 + (nf * 16 + l16) * 128 + ks * 32 + lg * 8);
      acc[0][nf] = __builtin_amdgcn_mfma_f32_16x16x32_f16(af[0], bf, acc[0][nf], 0, 0, 0);
      acc[1][nf] = __builtin_amdgcn_mfma_f32_16x16x32_f16(af[1], bf, acc[1][nf], 0, 0, 0);
    }
  }

  #pragma unroll
  for (int mr = 0; mr < 2; ++mr)
    #pragma unroll
    for (int nf = 0; nf < 8; ++nf)
      #pragma unroll
      for (int i = 0; i < 4; ++i)
        out[(size_t)(m0 + w * 32 + mr * 16 + lg * 4 + i) * 128 + nf * 16 + l16] = acc[mr][nf][i];
}

extern "C" void kernel_launch(void* const* d_in, const int* in_sizes, int n_in,
                              void* d_out, int out_size, void* d_ws, size_t ws_size,
                              hipStream_t stream){
  const float* frames      = (const float*)d_in[0];
  const float* Wq          = (const float*)d_in[1];
  const float* Wk          = (const float*)d_in[2];
  const float* Wv          = (const float*)d_in[3];
  const float* Wo          = (const float*)d_in[4];
  const float* temp_emb    = (const float*)d_in[5];
  const float* spatial_emb = (const float*)d_in[6];

  u16* WT    = (u16*)d_ws;                      // [4][128][128] fp16 (n-major)
  u16* se_h  = WT + 4 * 16384;                  // [25][128] fp16
  u16* Qb    = WT + 68736;                      // [N_][128] fp16 Q, then fp16 attnout
  u16* Kb    = (u16*)d_out;                     // [N_][128] fp16 K — reuse output buffer
  u16* Vb    = Kb + (size_t)N_ * 128;           // [N_][128] fp16 V — exactly fills d_out
  float* out = (float*)d_out;

  wt_kernel<<<269, 256, 0, stream>>>(Wq, Wk, Wv, Wo, spatial_emb, WT, se_h);
  qkv_kernel<<<N_ / 128, 256, 0, stream>>>(frames, WT, Qb, Kb, Vb, temp_emb, spatial_emb);
  attn_kernel<<<NS_ / 8, 256, 0, stream>>>(Kb, Vb, Qb, se_h);
  out_kernel<<<N_ / 128, 256, 0, stream>>>(Qb, WT + 3 * 16384, out);
}

// Round 18
// 301.010 us; speedup vs baseline: 1.1941x; 1.1941x over previous
//
#include <hip/hip_runtime.h>
#include <cstdint>
#include <cstddef>

#define T_ 3
#define B_ 2
#define Y_ 192
#define X_ 192
#define YX_ 36864          // Y_*X_
#define N_ 221184          // T_*B_*Y_*X_
#define NS_ 73728          // B_*Y_*X_

typedef __attribute__((ext_vector_type(8))) _Float16 h16x8;
typedef __attribute__((ext_vector_type(4))) float f32x4;
typedef __attribute__((ext_vector_type(2))) float f32x2;
typedef __attribute__((ext_vector_type(2))) _Float16 h16x2;
typedef unsigned short u16;
typedef unsigned int u32;

__device__ __forceinline__ u16 f2h(float f){
  return __builtin_bit_cast(u16, (_Float16)f);   // v_cvt_f16_f32, RNE
}
__device__ __forceinline__ int clampi(int v, int lo, int hi){ return v < lo ? lo : (v > hi ? hi : v); }
__device__ __forceinline__ h16x2 shflh(h16x2 v, int m){
  u32 u = __builtin_bit_cast(u32, v);
  u = __shfl_xor(u, m);
  return __builtin_bit_cast(h16x2, u);
}

// fp16 packed dot: v_dot2_f32_f16 (VOP3P)
#if __has_builtin(__builtin_amdgcn_fdot2)
__device__ __forceinline__ float dot2h(u32 a, u32 b, float c){
  return __builtin_amdgcn_fdot2(__builtin_bit_cast(h16x2, a),
                                __builtin_bit_cast(h16x2, b), c, false);
}
#else
__device__ __forceinline__ float dot2h(u32 a, u32 b, float c){
  const h16x2 ha = __builtin_bit_cast(h16x2, a);
  const h16x2 hb = __builtin_bit_cast(h16x2, b);
  return fmaf((float)ha.y, (float)hb.y, fmaf((float)ha.x, (float)hb.x, c));
}
#endif

#if __has_builtin(__builtin_amdgcn_exp2f)
__device__ __forceinline__ float fexp2(float x){ return __builtin_amdgcn_exp2f(x); }
#else
__device__ __forceinline__ float fexp2(float x){ return exp2f(x); }
#endif

// Q prescale: 1/sqrt(F) * log2(e), so score exp() becomes exp2() with no extra mul
#define QSCALE 0.36067376022224085f

// ---------------- kernel 0: weights -> fp16 n-major; spatial_emb -> fp16 ----------------
__global__ __launch_bounds__(256) void wt_kernel(
    const float* __restrict__ Wq, const float* __restrict__ Wk,
    const float* __restrict__ Wv, const float* __restrict__ Wo,
    const float* __restrict__ spatial_emb, u16* __restrict__ WT, u16* __restrict__ se_h){
  int idx = blockIdx.x * 256 + threadIdx.x;
  if (idx < 65536){
    int g = idx >> 14;
    int r = (idx >> 7) & 127;                   // k
    int c = idx & 127;                          // n
    const float* W = (g == 0) ? Wq : (g == 1) ? Wk : (g == 2) ? Wv : Wo;
    WT[g * 16384 + c * 128 + r] = f2h(W[r * 128 + c]);
  } else if (idx < 65536 + 3200){
    se_h[idx - 65536] = f2h(spatial_emb[idx - 65536]);
  }
}

// ---------------- kernel 1: fused QKV projection, persistent A-frags, fp16 MFMA ----------
// One block = 128 rows. A-tile loaded ONCE into fp16 register fragments (1 cvt/elem),
// g-loop {Q,K,V}: 64 MFMA + full-width 64KB-LDS epilogue (2 barriers per g).
// launch_bounds(256,2): VGPR budget 256 -> ~115 live state fits, NO spill (R17 lesson:
// never hint an occupancy whose VGPR cap is below the live state).
__global__ __launch_bounds__(256, 2) void qkv_kernel(
    const float* __restrict__ frames, const u16* __restrict__ WT,
    u16* __restrict__ Qb, u16* __restrict__ Kb, u16* __restrict__ Vb,
    const float* __restrict__ temp_emb, const float* __restrict__ spatial_emb){
  __shared__ float tile[128 * 128];
  const int tid = threadIdx.x;
  const int w = tid >> 6, l = tid & 63;
  const int l16 = l & 15, lg = l >> 4;
  const int m0 = blockIdx.x * 128;

  // ---- load A fragments once (fp16), reused by all 3 GEMMs ----
  h16x8 af[4][2];
  #pragma unroll
  for (int ks = 0; ks < 4; ++ks)
    #pragma unroll
    for (int mr = 0; mr < 2; ++mr){
      const float* ap = frames + (size_t)(m0 + w * 32 + mr * 16 + l16) * 128 + ks * 32 + lg * 8;
      const f32x4 a0 = *(const f32x4*)ap;
      const f32x4 a1 = *(const f32x4*)(ap + 4);
      h16x8 t;
      t[0] = (_Float16)a0[0]; t[1] = (_Float16)a0[1];
      t[2] = (_Float16)a0[2]; t[3] = (_Float16)a0[3];
      t[4] = (_Float16)a1[0]; t[5] = (_Float16)a1[1];
      t[6] = (_Float16)a1[2]; t[7] = (_Float16)a1[3];
      af[ks][mr] = t;
    }

  #pragma unroll
  for (int g = 0; g < 3; ++g){
    const u16* wt = WT + g * 16384;
    f32x4 acc[2][8];
    #pragma unroll
    for (int mr = 0; mr < 2; ++mr)
      #pragma unroll
      for (int nf = 0; nf < 8; ++nf)
        acc[mr][nf] = (f32x4){0.f, 0.f, 0.f, 0.f};

    #pragma unroll
    for (int ks = 0; ks < 4; ++ks)
      #pragma unroll
      for (int nf = 0; nf < 8; ++nf){
        const h16x8 bf = *(const h16x8*)(wt + (nf * 16 + l16) * 128 + ks * 32 + lg * 8);
        acc[0][nf] = __builtin_amdgcn_mfma_f32_16x16x32_f16(af[ks][0], bf, acc[0][nf], 0, 0, 0);
        acc[1][nf] = __builtin_amdgcn_mfma_f32_16x16x32_f16(af[ks][1], bf, acc[1][nf], 0, 0, 0);
      }

    if (g > 0) __syncthreads();                 // previous epilogue reads done
    #pragma unroll
    for (int mr = 0; mr < 2; ++mr)
      #pragma unroll
      for (int nf = 0; nf < 8; ++nf)
        #pragma unroll
        for (int i = 0; i < 4; ++i)
          tile[(w * 32 + mr * 16 + lg * 4 + i) * 128 + nf * 16 + l16] = acc[mr][nf][i];
    __syncthreads();

    u16* outp = (g == 0) ? Qb : (g == 1) ? Kb : Vb;
    #pragma unroll
    for (int it = 0; it < 16; ++it){
      const int idx = it * 256 + tid;
      const int r = idx >> 5;
      const int c4 = (idx & 31) * 4;
      f32x4 v = *(const f32x4*)&tile[r * 128 + c4];
      const int p = m0 + r;
      const int t = p / (B_ * YX_);
      if (g <= 1){                          // temporal emb for Q and K
        const float* te = temp_emb + t * 128 + c4;
        v[0] += te[0]; v[1] += te[1]; v[2] += te[2]; v[3] += te[3];
      }
      if (g == 0){                          // query spatial emb + QSCALE prescale
        const int yx = p % YX_;
        const int y = yx / X_, x = yx % X_;
        const int yrel = y - clampi(y, 2, Y_ - 3) + 2;
        const int xrel = x - clampi(x, 2, X_ - 3) + 2;
        const float* se = spatial_emb + (yrel * 5 + xrel) * 128 + c4;
        v[0] = (v[0] + se[0]) * QSCALE; v[1] = (v[1] + se[1]) * QSCALE;
        v[2] = (v[2] + se[2]) * QSCALE; v[3] = (v[3] + se[3]) * QSCALE;
      }
      uint2 pk;                             // Q,K,V all packed fp16
      pk.x = (u32)f2h(v[0]) | ((u32)f2h(v[1]) << 16);
      pk.y = (u32)f2h(v[2]) | ((u32)f2h(v[3]) << 16);
      *(uint2*)(outp + (size_t)p * 128 + c4) = pk;
    }
  }
}

// ---------------- kernel 2: scalar attention, 2 sites x 4 key-slots x 8 heads per wave ----------
// lane (s2=l>>5, slot=(l>>3)&3, h=l&7): site s2, head h (16ch), keys slot, slot+4, ...
// V fp16, PV accumulated as fp16 pairs via v_pk_fma_f16 (zero unpack); merge shuffles
// one u32 per pair. LDS 39KB -> 4 blocks/CU, 128-VGPR budget, no spill. Output fp16.
__global__ __launch_bounds__(256) void attn_kernel(
    const u16* __restrict__ Kb, const u16* __restrict__ Vb,
    u16* __restrict__ Qb, const u16* __restrict__ se_h){
  __shared__ float qse[4][2][1200];         // [wave][site2][q*200 + s*8 + h] (pad -> 4 blocks/CU)
  __shared__ u32 tbl[80];                   // byte offset (x256) | s*8 in low byte
  const int tid = threadIdx.x;
  const int w = tid >> 6, l = tid & 63;
  const int s2 = l >> 5, slot = (l >> 3) & 3, h = l & 7;

  if (tid < 80){                            // offset table (padded: 75..79 -> key 74)
    const int kk = tid > 74 ? 74 : tid;
    const int t = kk / 25, s = kk - t * 25;
    const int dy = s / 5, dx = s - dy * 5;
    tbl[tid] = (u32)((((t * (B_ * Y_) + dy) * X_ + dx) * 256) | (s * 8));
  }

  // XCD-aware swizzle: 9216 blocks = 8 XCDs x 1152 contiguous (48-row slab each)
  const int bid = blockIdx.x;
  const int sw = (bid & 7) * 1152 + (bid >> 3);
  const int site = sw * 8 + w * 2 + s2;
  const int b = site / YX_;
  const int yx = site % YX_;
  const int y = yx / X_, x = yx % X_;
  const int yc = clampi(y, 2, 189), xc = clampi(x, 2, 189);
  const u32 sbase = (u32)(((b * Y_ + (yc - 2)) * X_ + (xc - 2)) * 256 + h * 32);
  const char* Kc = (const char*)Kb;
  const char* Vc = (const char*)Vb;

  // Q packed fp16 (prescaled by QSCALE, + temp & query-spatial emb)
  u32 qp[3][8];
  #pragma unroll
  for (int q = 0; q < 3; ++q){
    const u16* qptr = Qb + ((size_t)((q * B_ + b) * Y_ + y) * X_ + x) * 128 + h * 16;
    const uint4 a = *(const uint4*)qptr;
    const uint4 c = *(const uint4*)(qptr + 8);
    qp[q][0] = a.x; qp[q][1] = a.y; qp[q][2] = a.z; qp[q][3] = a.w;
    qp[q][4] = c.x; qp[q][5] = c.y; qp[q][6] = c.z; qp[q][7] = c.w;
  }

  // qse[q][so][h] = Qs . spatial_emb[so] (per head), so striped over the 4 slots
  float* qsl = &qse[w][s2][0];
  #pragma unroll
  for (int sj = 0; sj < 7; ++sj){
    const int so = sj * 4 + slot;
    if (so < 25){
      const u16* sp = se_h + so * 128 + h * 16;
      const uint4 e0 = *(const uint4*)sp;
      const uint4 e1 = *(const uint4*)(sp + 8);
      u32 ep[8] = {e0.x, e0.y, e0.z, e0.w, e1.x, e1.y, e1.z, e1.w};
      #pragma unroll
      for (int q = 0; q < 3; ++q){
        float d = 0.f;
        #pragma unroll
        for (int i = 0; i < 8; ++i) d = dot2h(qp[q][i], ep[i], d);
        qsl[q * 200 + so * 8 + h] = d;
      }
    }
  }
  __syncthreads();

  // preload ALL 19 table entries into registers: no LDS reads on the address path
  u32 ev[19];
  #pragma unroll
  for (int j = 0; j < 19; ++j) ev[j] = tbl[j * 4 + slot];

  float ll[3] = {0.f, 0.f, 0.f};
  h16x2 acc[3][8];
  #pragma unroll
  for (int q = 0; q < 3; ++q)
    #pragma unroll
    for (int i = 0; i < 8; ++i) acc[q][i] = (h16x2){(_Float16)0.f, (_Float16)0.f};

  #pragma unroll
  for (int j = 0; j < 19; ++j){
    const u32 e = ev[j];
    const u32 boff = sbase + (e & 0xffffff00u);
    const int s8 = (int)(e & 0xffu);
    const uint4 k0 = *(const uint4*)(Kc + boff);
    const uint4 k1 = *(const uint4*)(Kc + boff + 16);
    const uint4 v0 = *(const uint4*)(Vc + boff);
    const uint4 v1 = *(const uint4*)(Vc + boff + 16);
    h16x2 hv[8];
    hv[0] = __builtin_bit_cast(h16x2, v0.x); hv[1] = __builtin_bit_cast(h16x2, v0.y);
    hv[2] = __builtin_bit_cast(h16x2, v0.z); hv[3] = __builtin_bit_cast(h16x2, v0.w);
    hv[4] = __builtin_bit_cast(h16x2, v1.x); hv[5] = __builtin_bit_cast(h16x2, v1.y);
    hv[6] = __builtin_bit_cast(h16x2, v1.z); hv[7] = __builtin_bit_cast(h16x2, v1.w);

    #pragma unroll
    for (int q = 0; q < 3; ++q){
      // two independent 4-deep dot2 chains (halved critical path)
      float d1 = qsl[q * 200 + s8 + h];
      d1 = dot2h(qp[q][0], k0.x, d1);
      d1 = dot2h(qp[q][1], k0.y, d1);
      d1 = dot2h(qp[q][2], k0.z, d1);
      d1 = dot2h(qp[q][3], k0.w, d1);
      float d2 = dot2h(qp[q][4], k1.x, 0.f);
      d2 = dot2h(qp[q][5], k1.y, d2);
      d2 = dot2h(qp[q][6], k1.z, d2);
      d2 = dot2h(qp[q][7], k1.w, d2);
      float p = fexp2(d1 + d2);
      if (j == 18 && slot == 3) p = 0.f;    // key 75 is padding
      ll[q] += p;
      const _Float16 ph = (_Float16)p;
      h16x2 pp; pp.x = ph; pp.y = ph;
      #pragma unroll
      for (int i = 0; i < 8; ++i) acc[q][i] += pp * hv[i];   // v_pk_fma_f16
    }
  }

  // merge across the 4 key-slot groups (lanes xor 8/16 share the same site & head)
  #pragma unroll
  for (int q = 0; q < 3; ++q){
    ll[q] += __shfl_xor(ll[q], 8);
    ll[q] += __shfl_xor(ll[q], 16);
    #pragma unroll
    for (int i = 0; i < 8; ++i){
      acc[q][i] += shflh(acc[q][i], 8);     // one u32 shuffle + one v_pk_add_f16
      acc[q][i] += shflh(acc[q][i], 16);
    }
  }

  // slot q (<3) stores query-frame q's output (fp16) over its site's Q row
  #pragma unroll
  for (int q = 0; q < 3; ++q){
    if (slot == q){
      const float inv = 1.0f / ll[q];
      uint4 o0, o1;
      {
        const float a0 = (float)acc[q][0].x * inv, a1 = (float)acc[q][0].y * inv;
        const float a2 = (float)acc[q][1].x * inv, a3 = (float)acc[q][1].y * inv;
        const float a4 = (float)acc[q][2].x * inv, a5 = (float)acc[q][2].y * inv;
        const float a6 = (float)acc[q][3].x * inv, a7 = (float)acc[q][3].y * inv;
        o0.x = (u32)f2h(a0) | ((u32)f2h(a1) << 16);
        o0.y = (u32)f2h(a2) | ((u32)f2h(a3) << 16);
        o0.z = (u32)f2h(a4) | ((u32)f2h(a5) << 16);
        o0.w = (u32)f2h(a6) | ((u32)f2h(a7) << 16);
      }
      {
        const float a0 = (float)acc[q][4].x * inv, a1 = (float)acc[q][4].y * inv;
        const float a2 = (float)acc[q][5].x * inv, a3 = (float)acc[q][5].y * inv;
        const float a4 = (float)acc[q][6].x * inv, a5 = (float)acc[q][6].y * inv;
        const float a6 = (float)acc[q][7].x * inv, a7 = (float)acc[q][7].y * inv;
        o1.x = (u32)f2h(a0) | ((u32)f2h(a1) << 16);
        o1.y = (u32)f2h(a2) | ((u32)f2h(a3) << 16);
        o1.z = (u32)f2h(a4) | ((u32)f2h(a5) << 16);
        o1.w = (u32)f2h(a6) | ((u32)f2h(a7) << 16);
      }
      u16* dst = Qb + ((size_t)((q * B_ + b) * Y_ + y) * X_ + x) * 128 + h * 16;
      *(uint4*)dst = o0;
      *(uint4*)(dst + 8) = o1;
    }
  }
}

// ---------------- kernel 3: output projection (attnout x Wout), fp16 MFMA ----------------
__global__ __launch_bounds__(256) void out_kernel(
    const u16* __restrict__ Ab, const u16* __restrict__ WT3, float* __restrict__ out){
  const int tid = threadIdx.x;
  const int w = tid >> 6, l = tid & 63;
  const int l16 = l & 15, lg = l >> 4;
  const int m0 = blockIdx.x * 128;

  f32x4 acc[2][8];
  #pragma unroll
  for (int mr = 0; mr < 2; ++mr)
    #pragma unroll
    for (int nf = 0; nf < 8; ++nf)
      acc[mr][nf] = (f32x4){0.f, 0.f, 0.f, 0.f};

  #pragma unroll
  for (int ks = 0; ks < 4; ++ks){
    h16x8 af[2];
    #pragma unroll
    for (int mr = 0; mr < 2; ++mr)
      af[mr] = *(const h16x8*)(Ab + (size_t)(m0 + w * 32 + mr * 16 + l16) * 128 + ks * 32 + lg * 8);
    #pragma unroll
    for (int nf = 0; nf < 8; ++nf){
      const h16x8 bf = *(const h16x8*)(WT3 + (nf * 16 + l16) * 128 + ks * 32 + lg * 8);
      acc[0][nf] = __builtin_amdgcn_mfma_f32_16x16x32_f16(af[0], bf, acc[0][nf], 0, 0, 0);
      acc[1][nf] = __builtin_amdgcn_mfma_f32_16x16x32_f16(af[1], bf, acc[1][nf], 0, 0, 0);
    }
  }

  #pragma unroll
  for (int mr = 0; mr < 2; ++mr)
    #pragma unroll
    for (int nf = 0; nf < 8; ++nf)
      #pragma unroll
      for (int i = 0; i < 4; ++i)
        out[(size_t)(m0 + w * 32 + mr * 16 + lg * 4 + i) * 128 + nf * 16 + l16] = acc[mr][nf][i];
}

extern "C" void kernel_launch(void* const* d_in, const int* in_sizes, int n_in,
                              void* d_out, int out_size, void* d_ws, size_t ws_size,
                              hipStream_t stream){
  const float* frames      = (const float*)d_in[0];
  const float* Wq          = (const float*)d_in[1];
  const float* Wk          = (const float*)d_in[2];
  const float* Wv          = (const float*)d_in[3];
  const float* Wo          = (const float*)d_in[4];
  const float* temp_emb    = (const float*)d_in[5];
  const float* spatial_emb = (const float*)d_in[6];

  u16* WT    = (u16*)d_ws;                      // [4][128][128] fp16 (n-major)
  u16* se_h  = WT + 4 * 16384;                  // [25][128] fp16
  u16* Qb    = WT + 68736;                      // [N_][128] fp16 Q, then fp16 attnout
  u16* Kb    = (u16*)d_out;                     // [N_][128] fp16 K — reuse output buffer
  u16* Vb    = Kb + (size_t)N_ * 128;           // [N_][128] fp16 V — exactly fills d_out
  float* out = (float*)d_out;

  wt_kernel<<<269, 256, 0, stream>>>(Wq, Wk, Wv, Wo, spatial_emb, WT, se_h);
  qkv_kernel<<<N_ / 128, 256, 0, stream>>>(frames, WT, Qb, Kb, Vb, temp_emb, spatial_emb);
  attn_kernel<<<NS_ / 8, 256, 0, stream>>>(Kb, Vb, Qb, se_h);
  out_kernel<<<N_ / 128, 256, 0, stream>>>(Qb, WT + 3 * 16384, out);
}